// Round 1
// 136.966 us; speedup vs baseline: 1.0289x; 1.0289x over previous
//
#include <hip/hip_runtime.h>

#define EPS 1e-3f

// ---- ws layout (float offsets) ----
#define OFF_PGAP   0         // 65536  : per-(block,channel) gap partial sums [256][256]
#define OFF_PART   65536     // 98304  : qkv split-K partials [3][32][4][256]
#define OFF_A      163840    // 1024   : per-channel affine scale A[b][c]
#define OFF_BIAS   164864    // 16     : folded qkv bias [4][3]
#define OFF_QS     164880    // 16384  : spatial q  [4][4096]
#define OFF_KS     181264    // 16384  : spatial k
#define OFF_VS     197648    // 16384  : spatial v

// K1: gap partial sums, float4 (16B/lane) loads. 256 blocks x 256 threads.
// Side duty: warm the 1MB of attention weights into L3 (4KB per block) so the
// downstream latency-starved consumers (k_qkvmat slices, k_mid's wp read) hit
// L3 (~250-450cy) instead of cold HBM (~900cy).
__global__ __launch_bounds__(256) void k_gap(const float* __restrict__ x,
                                             const float* __restrict__ wq,
                                             const float* __restrict__ wk,
                                             const float* __restrict__ wv,
                                             const float* __restrict__ wp,
                                             float* __restrict__ pgap) {
    __shared__ float4 red[256];          // [pg=4][cg=64]
    int blk = blockIdx.x;                // 0..255 ; pixel base = blk*64
    int t = threadIdx.x;

    // issue weight-warm load early; consumed (kept live) after the main loop
    const float* wmat = (blk < 64) ? wq : (blk < 128) ? wk : (blk < 192) ? wv : wp;
    float4 wv4 = *(const float4*)(wmat + (size_t)(blk & 63) * 1024 + 4 * t);

    int cg = t & 63;                     // channel quad: channels 4cg..4cg+3
    int pg = t >> 6;                     // pixel group (wave id): pixels pg*16..+15
    const float* xp = x + ((size_t)blk * 64 + pg * 16) * 256 + 4 * cg;
    float4 s = make_float4(0.f, 0.f, 0.f, 0.f);
    #pragma unroll
    for (int u = 0; u < 16; ++u) {
        float4 v = *(const float4*)(xp + (size_t)u * 256);
        s.x += v.x; s.y += v.y; s.z += v.z; s.w += v.w;
    }
    red[pg * 64 + cg] = s;
    asm volatile("" :: "v"(wv4.x), "v"(wv4.y), "v"(wv4.z), "v"(wv4.w)); // anti-DCE
    __syncthreads();
    if (t < 64) {
        float4 a = red[t], b4 = red[64 + t], c4 = red[128 + t], d4 = red[192 + t];
        float4 o = make_float4(a.x + b4.x + c4.x + d4.x,
                               a.y + b4.y + c4.y + d4.y,
                               a.z + b4.z + c4.z + d4.z,
                               a.w + b4.w + c4.w + d4.w);
        *(float4*)(pgap + blk * 256 + 4 * t) = o;
    }
}

// K2a: split-K q/k/v weight matmul. 96 blocks = 3 mats x 32 row-groups (8 rows each),
// 256 threads (thread = output column). Each block recomputes gn for its 8 rows from
// pgap (cheap, cache-hit), reads an 8KB weight slice (parallel across 96 CUs instead
// of 4), writes per-group partials for all 4 batches.
__global__ __launch_bounds__(256) void k_qkvmat(
    const float* __restrict__ pgap,
    const float* __restrict__ cag, const float* __restrict__ cab,
    const float* __restrict__ cam, const float* __restrict__ cav,
    const float* __restrict__ wq, const float* __restrict__ wk,
    const float* __restrict__ wv,
    float* __restrict__ part)
{
    __shared__ float gpart[4][8][4];     // [b][row][quarter]
    __shared__ float gn_s[4][8];
    int blk = blockIdx.x;
    int m = blk >> 5;                    // 0=q 1=k 2=v
    int g = blk & 31;                    // row group
    int r0 = g * 8;
    int t = threadIdx.x;
    const float* W = (m == 0) ? wq : (m == 1) ? wk : wv;

    // gn for rows r0..r0+7, all 4 batches: sum 64 pgap chunks per (b,row)
    if (t < 128) {
        int b = t >> 5, row = (t >> 2) & 7, p = t & 3;
        const float* pgp = pgap + ((size_t)(b * 64 + p * 16)) * 256 + r0 + row;
        float s = 0.f;
        #pragma unroll
        for (int ch = 0; ch < 16; ++ch) s += pgp[(size_t)ch * 256];
        gpart[b][row][p] = s;
    }
    __syncthreads();
    if (t < 32) {
        int b = t >> 3, row = t & 7;
        float gsum = gpart[b][row][0] + gpart[b][row][1]
                   + gpart[b][row][2] + gpart[b][row][3];
        float gv = gsum * (1.0f / 4096.0f);
        int c = r0 + row;
        float sc = cag[c] * rsqrtf(cav[c] + EPS);
        gn_s[b][row] = gv * sc + (cab[c] - cam[c] * sc);
    }
    __syncthreads();

    float a0 = 0.f, a1 = 0.f, a2 = 0.f, a3 = 0.f;
    const float* wp_ = W + (size_t)r0 * 256 + t;
    #pragma unroll
    for (int row = 0; row < 8; ++row) {
        float w = wp_[(size_t)row * 256];                 // coalesced 256B/wave
        a0 = fmaf(gn_s[0][row], w, a0);
        a1 = fmaf(gn_s[1][row], w, a1);
        a2 = fmaf(gn_s[2][row], w, a2);
        a3 = fmaf(gn_s[3][row], w, a3);
    }
    float* o = part + (size_t)(m * 32 + g) * 1024 + t;    // [m][g][b][c]
    o[0] = a0; o[256] = a1; o[512] = a2; o[768] = a3;
}

// K2b: middle stage tail. 4 blocks (one per batch) x 512 threads.
// Reduce split-K partials -> channel softmax/att -> wp matmul (L3-warm) ->
// sigmoid -> percentile -> folded affine A, bias.
__global__ __launch_bounds__(512) void k_mid(
    const float* __restrict__ part,
    const float* __restrict__ wp,
    const float* __restrict__ bng, const float* __restrict__ bnb,
    const float* __restrict__ bnm, const float* __restrict__ bnv,
    const float* __restrict__ wqkv,
    float* __restrict__ Aout, float* __restrict__ biasOut)
{
    __shared__ float sq[256], sk[256], sv[256], att[256], cm[256], Bc[256];
    __shared__ float red[2048];
    __shared__ float swqkv[768];
    __shared__ float t25, t26, thr;

    int b = blockIdx.x;
    int t = threadIdx.x;                 // 0..511
    int cg = t & 63;                     // col group
    int rg = t >> 6;                     // row group (wave-uniform)
    int c4 = cg * 4;

    // stage wqkv early (Phase F consumer)
    if (t < 384) {
        swqkv[t] = wqkv[t];
        swqkv[t + 384] = wqkv[t + 384];
    }

    // ---- reduce split-K partials: q,k (512-way) and v (256-way) ----
    {
        int m = t >> 8, c = t & 255;     // m=0: q ; m=1: k
        const float* p = part + (size_t)m * 32768 + b * 256 + c;
        float s = 0.f;
        #pragma unroll
        for (int g2 = 0; g2 < 32; ++g2) s += p[(size_t)g2 * 1024];
        if (m == 0) sq[c] = s; else sk[c] = s;
        if (t < 256) {
            const float* p2 = part + (size_t)2 * 32768 + b * 256 + t;
            float s2 = 0.f;
            #pragma unroll
            for (int g2 = 0; g2 < 32; ++g2) s2 += p2[(size_t)g2 * 1024];
            sv[t] = s2;
        }
    }
    __syncthreads();

    // ---- Phase C: channel attention row c (rank-1 logits), j split over halves ----
    {
        int h = t >> 8, c = t & 255;
        float a = sq[c];
        int jb = h * 128;
        float mx = -1e30f;
        #pragma unroll 8
        for (int j = 0; j < 128; ++j) mx = fmaxf(mx, a * sk[jb + j]);
        float den = 0.f, num = 0.f;
        #pragma unroll 4
        for (int j = 0; j < 128; ++j) {
            float e = __expf(a * sk[jb + j] - mx);
            den += e; num = fmaf(e, sv[jb + j], num);
        }
        red[h * 256 + c] = mx;
        red[512 + h * 256 + c] = den;
        red[1024 + h * 256 + c] = num;
    }
    __syncthreads();
    if (t < 256) {
        float m0 = red[t], m1 = red[256 + t];
        float M = fmaxf(m0, m1);
        float s0 = __expf(m0 - M), s1 = __expf(m1 - M);
        float den = red[512 + t] * s0 + red[768 + t] * s1;
        float num = red[1024 + t] * s0 + red[1280 + t] * s1;
        att[t] = num / den;
    }
    __syncthreads();

    // ---- Phase D: cm = sigmoid(att @ wp), float4 cols, rows split 8 ways ----
    {
        int rbase = rg * 32;
        float4 ac = make_float4(0.f, 0.f, 0.f, 0.f);
        const float* wpp = wp + (size_t)rbase * 256 + c4;
        #pragma unroll 8
        for (int i = 0; i < 32; ++i) {
            float g = att[rbase + i];
            float4 w = *(const float4*)(wpp + (size_t)i * 256);
            ac.x = fmaf(g, w.x, ac.x); ac.y = fmaf(g, w.y, ac.y);
            ac.z = fmaf(g, w.z, ac.z); ac.w = fmaf(g, w.w, ac.w);
        }
        *(float4*)(red + rg * 256 + c4) = ac;
    }
    __syncthreads();
    if (t < 256) {
        float ac = 0.f;
        #pragma unroll
        for (int r = 0; r < 8; ++r) ac += red[r * 256 + t];
        cm[t] = 1.0f / (1.0f + __expf(-ac));
    }
    __syncthreads();

    // ---- Phase E: 10th percentile (linear): s[25] + 0.5*(s[26]-s[25]) ----
    if (t < 256) {
        float my = cm[t];
        int rank = 0;
        for (int j = 0; j < 256; ++j) {
            float o = cm[j];
            rank += (o < my) ? 1 : ((o == my && j < t) ? 1 : 0);
        }
        if (rank == 25) t25 = my;        // ranks form a permutation -> unique writers
        if (rank == 26) t26 = my;
    }
    __syncthreads();
    if (t == 0) thr = t25 + 0.5f * (t26 - t25);
    __syncthreads();

    // ---- Phase F: fold affine A,B; bias = B @ w_qkv (wqkv staged in LDS) ----
    if (t < 256) {
        float s2 = bng[t] * rsqrtf(bnv[t] + EPS);
        float o2 = bnb[t] - bnm[t] * s2;
        float cc = cm[t];
        float pm = (cc > thr) ? cc : 0.f;
        Aout[b * 256 + t] = (1.f + cc) * s2 * pm;
        Bc[t] = o2 * pm;
    }
    __syncthreads();
    if (t < 3) {
        float s3 = 0.f;
        for (int ch = 0; ch < 256; ++ch) s3 = fmaf(Bc[ch], swqkv[ch * 3 + t], s3);
        biasOut[b * 3 + t] = s3;
    }
}

// K3: qkv = (x*A + B) @ w_qkv. One wave per pixel, lane covers 4 channels. 1024 blocks x 256.
__global__ __launch_bounds__(256) void k_qkv(
    const float* __restrict__ x, const float* __restrict__ A,
    const float* __restrict__ wqkv, const float* __restrict__ bias,
    float* __restrict__ qs, float* __restrict__ ks, float* __restrict__ vs)
{
    int lane = threadIdx.x & 63;
    int wid = (blockIdx.x * 256 + threadIdx.x) >> 6;   // 0..4095 (wave-uniform)
    float4 wA = *(const float4*)(wqkv + 12 * lane);
    float4 wB = *(const float4*)(wqkv + 12 * lane + 4);
    float4 wC = *(const float4*)(wqkv + 12 * lane + 8);
    float w00 = wA.x, w01 = wA.y, w02 = wA.z;
    float w10 = wA.w, w11 = wB.x, w12 = wB.y;
    float w20 = wB.z, w21 = wB.w, w22 = wC.x;
    float w30 = wC.y, w31 = wC.z, w32 = wC.w;
    #pragma unroll
    for (int b = 0; b < 4; ++b) {
        int pix = b * 4096 + wid;
        float4 xv = *(const float4*)(x + (size_t)pix * 256 + 4 * lane);
        float4 A4 = *(const float4*)(A + b * 256 + 4 * lane);
        float t0 = xv.x * A4.x, t1 = xv.y * A4.y;
        float t2 = xv.z * A4.z, t3 = xv.w * A4.w;
        float q = t0 * w00 + t1 * w10 + t2 * w20 + t3 * w30;
        float k = t0 * w01 + t1 * w11 + t2 * w21 + t3 * w31;
        float v = t0 * w02 + t1 * w12 + t2 * w22 + t3 * w32;
        #pragma unroll
        for (int m = 1; m < 64; m <<= 1) {
            q += __shfl_xor(q, m, 64);
            k += __shfl_xor(k, m, 64);
            v += __shfl_xor(v, m, 64);
        }
        if (lane == 0) {
            qs[pix] = q + bias[b * 3 + 0];
            ks[pix] = k + bias[b * 3 + 1];
            vs[pix] = v + bias[b * 3 + 2];
        }
    }
}

// K4: fused spatial attention + output. 256 blocks = (b, 64 row-chunks) x 512 threads.
// Full batch K/V (32 KB) LDS-resident; global k-max/min -> exact row max, no flash
// combine; wave `sub` covers a 512-j slice (uniform LDS addr = broadcast); direct out.
__global__ __launch_bounds__(512) void k_attn2(
    const float* __restrict__ qs, const float* __restrict__ ks, const float* __restrict__ vs,
    float* __restrict__ out)
{
    __shared__ float4 skv[2048];          // (k0,v0,k1,v1) pairs for all 4096 j : 32 KB
    __shared__ float pden[8][64], pnum[8][64];
    __shared__ float rmax[8], rmin[8];
    int blk = blockIdx.x;                 // 256 = b(4) * ic(64)
    int b = blk >> 6, ic = blk & 63;
    int t = threadIdx.x;                  // 0..511
    int lane = t & 63, sub = t >> 6;      // sub = wave id (wave-uniform)
    int base = b * 4096;

    const float4* k4 = (const float4*)(ks + base);
    const float4* v4 = (const float4*)(vs + base);
    float kmx = -1e30f, kmn = 1e30f;
    #pragma unroll
    for (int u = 0; u < 2; ++u) {
        int i = t + u * 512;              // 0..1023 float4 rows
        float4 kk = k4[i], vv = v4[i];
        skv[i * 2]     = make_float4(kk.x, vv.x, kk.y, vv.y);
        skv[i * 2 + 1] = make_float4(kk.z, vv.z, kk.w, vv.w);
        kmx = fmaxf(kmx, fmaxf(fmaxf(kk.x, kk.y), fmaxf(kk.z, kk.w)));
        kmn = fminf(kmn, fminf(fminf(kk.x, kk.y), fminf(kk.z, kk.w)));
    }
    #pragma unroll
    for (int m2 = 1; m2 < 64; m2 <<= 1) {
        kmx = fmaxf(kmx, __shfl_xor(kmx, m2, 64));
        kmn = fminf(kmn, __shfl_xor(kmn, m2, 64));
    }
    if (lane == 0) { rmax[sub] = kmx; rmin[sub] = kmn; }
    __syncthreads();
    float mx = rmax[0], mn = rmin[0];
    #pragma unroll
    for (int s = 1; s < 8; ++s) { mx = fmaxf(mx, rmax[s]); mn = fminf(mn, rmin[s]); }

    int row = ic * 64 + lane;
    float a = qs[base + row];
    float m = (a >= 0.f) ? a * mx : a * mn;   // exact global row max (rank-1 logits)
    float den0 = 0.f, num0 = 0.f, den1 = 0.f, num1 = 0.f;
    const float4* sp = skv + sub * 256;       // this wave's 512-j slice
    #pragma unroll 4
    for (int j = 0; j < 256; ++j) {
        float4 kv = sp[j];                    // uniform addr -> broadcast, conflict-free
        float e0 = __expf(fmaf(a, kv.x, -m));
        float e1 = __expf(fmaf(a, kv.z, -m));
        den0 += e0; num0 = fmaf(e0, kv.y, num0);
        den1 += e1; num1 = fmaf(e1, kv.w, num1);
    }
    pden[sub][lane] = den0 + den1;
    pnum[sub][lane] = num0 + num1;
    __syncthreads();
    if (t < 64) {
        float den = 0.f, num = 0.f;
        #pragma unroll
        for (int s = 0; s < 8; ++s) { den += pden[s][t]; num += pnum[s][t]; }
        int r = ic * 64 + t;
        float vrow = (r & 1) ? skv[r >> 1].w : skv[r >> 1].y;   // v from LDS
        out[base + r] = vrow + num / den;
    }
}

extern "C" void kernel_launch(void* const* d_in, const int* in_sizes, int n_in,
                              void* d_out, int out_size, void* d_ws, size_t ws_size,
                              hipStream_t stream) {
    const float* x    = (const float*)d_in[0];
    const float* cag  = (const float*)d_in[1];
    const float* cab  = (const float*)d_in[2];
    const float* cam  = (const float*)d_in[3];
    const float* cav  = (const float*)d_in[4];
    const float* wq   = (const float*)d_in[5];
    const float* wk   = (const float*)d_in[6];
    const float* wv   = (const float*)d_in[7];
    const float* wp   = (const float*)d_in[8];
    const float* bng  = (const float*)d_in[9];
    const float* bnb  = (const float*)d_in[10];
    const float* bnm  = (const float*)d_in[11];
    const float* bnv  = (const float*)d_in[12];
    const float* wqkv = (const float*)d_in[13];

    float* ws   = (float*)d_ws;
    float* pgap = ws + OFF_PGAP;
    float* part = ws + OFF_PART;
    float* A    = ws + OFF_A;
    float* bias = ws + OFF_BIAS;
    float* qs   = ws + OFF_QS;
    float* ks   = ws + OFF_KS;
    float* vs   = ws + OFF_VS;

    k_gap<<<dim3(256), dim3(256), 0, stream>>>(x, wq, wk, wv, wp, pgap);
    k_qkvmat<<<dim3(96), dim3(256), 0, stream>>>(pgap, cag, cab, cam, cav,
                                                 wq, wk, wv, part);
    k_mid<<<dim3(4), dim3(512), 0, stream>>>(part, wp, bng, bnb, bnm, bnv, wqkv,
                                             A, bias);
    k_qkv<<<dim3(1024), dim3(256), 0, stream>>>(x, A, wqkv, bias, qs, ks, vs);
    k_attn2<<<dim3(256), dim3(512), 0, stream>>>(qs, ks, vs, (float*)d_out);
}